// Round 4
// baseline (396.179 us; speedup 1.0000x reference)
//
#include <hip/hip_runtime.h>

typedef __attribute__((ext_vector_type(4))) float  f32x4;
typedef __attribute__((ext_vector_type(8))) __bf16 bf16x8;

__device__ __forceinline__ unsigned short f2bf(float f) {
    unsigned int u = __float_as_uint(f);
    u += 0x7FFFu + ((u >> 16) & 1u);   // RNE
    return (unsigned short)(u >> 16);
}

#define S_LEN 2048
#define E_DIM 512
#define NH 64
#define DK 8

// ---------------------------------------------------------------------------
// Kernel 1: quantum projection + per-token attention over heads.
// One wave per token, lane = head. Inputs fp32. Writes the
// transpose(1,2).view-scrambled activation A (bf16, 16384 x 512) into d_ws.
// A[row, col]: row = b*2048 + h*32 + s/64 ; col = (s%64)*8 + d
// ---------------------------------------------------------------------------
__global__ __launch_bounds__(256) void attn_stage(
    const float* __restrict__ X,    // (8,2048,512) fp32
    const float* __restrict__ TH,   // (8,) fp32
    unsigned short* __restrict__ A) // ws: 16384 x 512 bf16
{
    __shared__ __align__(16) float ldsP[4][NH][DK];   // 8 KB
    const int wv = threadIdx.x >> 6;
    const int h  = threadIdx.x & 63;
    const int t  = blockIdx.x * 4 + wv;     // token id
    const int b  = t >> 11;
    const int s  = t & (S_LEN - 1);

    const float4 t0 = *(const float4*)(TH);
    const float4 t1 = *(const float4*)(TH + 4);

    const float4 x0 = *(const float4*)(X + (size_t)t * E_DIM + h * DK);
    const float4 x1 = *(const float4*)(X + (size_t)t * E_DIM + h * DK + 4);

    float p[DK];
    p[0] = __cosf(x0.x + t0.x); p[1] = __cosf(x0.y + t0.y);
    p[2] = __cosf(x0.z + t0.z); p[3] = __cosf(x0.w + t0.w);
    p[4] = __cosf(x1.x + t1.x); p[5] = __cosf(x1.y + t1.y);
    p[6] = __cosf(x1.z + t1.z); p[7] = __cosf(x1.w + t1.w);

    #pragma unroll
    for (int d = 0; d < DK; ++d) ldsP[wv][h][d] = p[d];
    __syncthreads();

    // scores row h: dot(p, proj[g]) / sqrt(8); g is wave-uniform -> LDS broadcast
    const float scale = 0.35355339059327373f;
    float sc[NH];
    float mx = -1e30f;
    #pragma unroll
    for (int g = 0; g < NH; ++g) {
        const float4 q0 = *(const float4*)&ldsP[wv][g][0];
        const float4 q1 = *(const float4*)&ldsP[wv][g][4];
        float dot = p[0]*q0.x + p[1]*q0.y + p[2]*q0.z + p[3]*q0.w
                  + p[4]*q1.x + p[5]*q1.y + p[6]*q1.z + p[7]*q1.w;
        dot *= scale;
        sc[g] = dot;
        mx = fmaxf(mx, dot);
    }
    float sum = 0.f;
    #pragma unroll
    for (int g = 0; g < NH; ++g) {
        const float e = __expf(sc[g] - mx);
        sc[g] = e;
        sum += e;
    }
    const float inv = 1.0f / sum;

    float a[DK] = {0.f,0.f,0.f,0.f,0.f,0.f,0.f,0.f};
    #pragma unroll
    for (int g = 0; g < NH; ++g) {
        const float4 q0 = *(const float4*)&ldsP[wv][g][0];
        const float4 q1 = *(const float4*)&ldsP[wv][g][4];
        const float w = sc[g];
        a[0] += w*q0.x; a[1] += w*q0.y; a[2] += w*q0.z; a[3] += w*q0.w;
        a[4] += w*q1.x; a[5] += w*q1.y; a[6] += w*q1.z; a[7] += w*q1.w;
    }

    unsigned int ow[4];
    #pragma unroll
    for (int d = 0; d < 4; ++d)
        ow[d] = (unsigned int)f2bf(a[2*d]*inv) | ((unsigned int)f2bf(a[2*d+1]*inv) << 16);
    uint4 outv; outv.x = ow[0]; outv.y = ow[1]; outv.z = ow[2]; outv.w = ow[3];

    const int row = (b << 11) + h * 32 + (s >> 6);
    const int col = (s & 63) * DK;
    *(uint4*)(A + (size_t)row * E_DIM + col) = outv;
}

// ---------------------------------------------------------------------------
// Prepass: convert W (512x512 fp32) -> bf16 in ws. 4 elems/thread.
// ---------------------------------------------------------------------------
__global__ __launch_bounds__(256) void convert_w(
    const float* __restrict__ W, unsigned short* __restrict__ Wb)
{
    const int i = blockIdx.x * 256 + threadIdx.x;     // 0..65535
    const float4 v = *(const float4*)(W + (size_t)i * 4);
    ushort4 o;
    o.x = f2bf(v.x); o.y = f2bf(v.y); o.z = f2bf(v.z); o.w = f2bf(v.w);
    *(ushort4*)(Wb + (size_t)i * 4) = o;
}

// ---------------------------------------------------------------------------
// Kernel 2: OUT = A @ W^T + bias.  M=16384, N=K=512. A,W bf16 (ws); bias fp32;
// OUT fp32 (reference output dtype). 128x128 tile, 4 waves (2x2),
// each wave 4x4 mfma 16x16x32 tiles. Register-mediated staging (m93 pattern).
// ---------------------------------------------------------------------------
#define BM 128
#define BN 128
#define BK 32

__global__ __launch_bounds__(256) void gemm_bias(
    const unsigned short* __restrict__ A,     // 16384 x 512 bf16 (ws)
    const unsigned short* __restrict__ W,     // 512 x 512 bf16 (ws)
    const float* __restrict__ BIAS,           // 512 fp32
    float* __restrict__ OUT)                  // 16384 x 512 fp32
{
    const int Kdim = 512;
    __shared__ __align__(16) unsigned short ldsA[BM * BK];  // 8 KB
    __shared__ __align__(16) unsigned short ldsB[BN * BK];  // 8 KB
    const int tid  = threadIdx.x;
    const int wave = tid >> 6;
    const int lane = tid & 63;
    const int quad = lane >> 4;
    const int l16  = lane & 15;
    const int m0 = blockIdx.x * BM;
    const int n0 = blockIdx.y * BN;
    const int wm = (wave & 1) * 64;
    const int wn = (wave >> 1) * 64;

    f32x4 acc[4][4] = {};

    for (int kb = 0; kb < Kdim; kb += BK) {
        uint4 av[2], wvv[2];
        int cc[2];
        #pragma unroll
        for (int i = 0; i < 2; ++i) {
            const int c  = tid + i * 256;       // chunk id 0..511
            const int r  = c >> 2;              // tile row 0..127
            const int ko = (c & 3) * 8;         // k offset in elems
            cc[i] = c;
            av[i]  = *(const uint4*)(A + (size_t)(m0 + r) * Kdim + kb + ko);
            wvv[i] = *(const uint4*)(W + (size_t)(n0 + r) * Kdim + kb + ko);
        }
        __syncthreads();   // previous iteration's readers done
        #pragma unroll
        for (int i = 0; i < 2; ++i) {
            *(uint4*)(ldsA + cc[i] * 8) = av[i];
            *(uint4*)(ldsB + cc[i] * 8) = wvv[i];
        }
        __syncthreads();   // staging visible

        bf16x8 bfr[4];
        #pragma unroll
        for (int ni = 0; ni < 4; ++ni)
            bfr[ni] = *(const bf16x8*)(ldsB + (wn + ni*16 + l16) * BK + quad * 8);
        #pragma unroll
        for (int mi = 0; mi < 4; ++mi) {
            const bf16x8 afr = *(const bf16x8*)(ldsA + (wm + mi*16 + l16) * BK + quad * 8);
            #pragma unroll
            for (int ni = 0; ni < 4; ++ni)
                acc[mi][ni] = __builtin_amdgcn_mfma_f32_16x16x32_bf16(
                    afr, bfr[ni], acc[mi][ni], 0, 0, 0);
        }
    }

    float bv[4];
    #pragma unroll
    for (int ni = 0; ni < 4; ++ni) bv[ni] = BIAS[n0 + wn + ni*16 + l16];

    #pragma unroll
    for (int mi = 0; mi < 4; ++mi) {
        #pragma unroll
        for (int ni = 0; ni < 4; ++ni) {
            const int n = n0 + wn + ni*16 + l16;
            #pragma unroll
            for (int r = 0; r < 4; ++r) {
                const int m = m0 + wm + mi*16 + quad*4 + r;   // C/D: row=(lane>>4)*4+reg
                OUT[(size_t)m * 512 + n] = acc[mi][ni][r] + bv[ni];
            }
        }
    }
}

extern "C" void kernel_launch(void* const* d_in, const int* in_sizes, int n_in,
                              void* d_out, int out_size, void* d_ws, size_t ws_size,
                              hipStream_t stream) {
    const float* X  = (const float*)d_in[0];   // x fp32
    const float* TH = (const float*)d_in[1];   // theta fp32
    const float* W  = (const float*)d_in[2];   // W_combine fp32
    const float* BI = (const float*)d_in[3];   // b_combine fp32
    float* OUT = (float*)d_out;                // fp32 (reference output dtype)

    unsigned short* A  = (unsigned short*)d_ws;                        // 16 MiB
    unsigned short* Wb = (unsigned short*)((char*)d_ws + (16u << 20)); // 512 KiB

    attn_stage<<<dim3(4096), dim3(256), 0, stream>>>(X, TH, A);
    convert_w<<<dim3(256), dim3(256), 0, stream>>>(W, Wb);
    gemm_bias<<<dim3(128, 4), dim3(256), 0, stream>>>(A, Wb, BI, OUT);
}

// Round 5
// 172.343 us; speedup vs baseline: 2.2988x; 2.2988x over previous
//
#include <hip/hip_runtime.h>

typedef __attribute__((ext_vector_type(4))) float  f32x4;
typedef __attribute__((ext_vector_type(8))) __bf16 bf16x8;

__device__ __forceinline__ unsigned short f2bf(float f) {
    unsigned int u = __float_as_uint(f);
    u += 0x7FFFu + ((u >> 16) & 1u);   // RNE
    return (unsigned short)(u >> 16);
}

#define S_LEN 2048
#define E_DIM 512
#define NH 64
#define DK 8

// ---------------------------------------------------------------------------
// Kernel 1: quantum projection + per-token attention over heads.
// One wave per token, lane = head. Inputs fp32. Writes the
// transpose(1,2).view-scrambled activation A (bf16, 16384 x 512) into d_ws.
// A[row, col]: row = b*2048 + h*32 + s/64 ; col = (s%64)*8 + d
//
// Single-pass softmax WITHOUT max subtraction: |score| <= 8/sqrt(8) = 2.83,
// so exp() in [0.059, 17] -- no overflow, no sc[64] array, no VGPR spill.
// (R4 profile: sc[64] spilled -> 602 MB scratch writes, 292 us.)
// ---------------------------------------------------------------------------
__global__ __launch_bounds__(256) void attn_stage(
    const float* __restrict__ X,    // (8,2048,512) fp32
    const float* __restrict__ TH,   // (8,) fp32
    unsigned short* __restrict__ A) // ws: 16384 x 512 bf16
{
    __shared__ __align__(16) float ldsP[4][NH][DK];   // 8 KB
    const int wv = threadIdx.x >> 6;
    const int h  = threadIdx.x & 63;
    const int t  = blockIdx.x * 4 + wv;     // token id
    const int b  = t >> 11;
    const int s  = t & (S_LEN - 1);

    const float4 t0 = *(const float4*)(TH);
    const float4 t1 = *(const float4*)(TH + 4);

    const float4 x0 = *(const float4*)(X + (size_t)t * E_DIM + h * DK);
    const float4 x1 = *(const float4*)(X + (size_t)t * E_DIM + h * DK + 4);

    float p[DK];
    p[0] = __cosf(x0.x + t0.x); p[1] = __cosf(x0.y + t0.y);
    p[2] = __cosf(x0.z + t0.z); p[3] = __cosf(x0.w + t0.w);
    p[4] = __cosf(x1.x + t1.x); p[5] = __cosf(x1.y + t1.y);
    p[6] = __cosf(x1.z + t1.z); p[7] = __cosf(x1.w + t1.w);

    #pragma unroll
    for (int d = 0; d < DK; ++d) ldsP[wv][h][d] = p[d];
    __syncthreads();

    // Fused scores+softmax+weighted sum, one LDS-broadcast pass over g.
    const float scale = 0.35355339059327373f;
    float sum = 0.f;
    float a[DK] = {0.f,0.f,0.f,0.f,0.f,0.f,0.f,0.f};
    #pragma unroll 8
    for (int g = 0; g < NH; ++g) {
        const float4 q0 = *(const float4*)&ldsP[wv][g][0];
        const float4 q1 = *(const float4*)&ldsP[wv][g][4];
        float dot = p[0]*q0.x + p[1]*q0.y + p[2]*q0.z + p[3]*q0.w
                  + p[4]*q1.x + p[5]*q1.y + p[6]*q1.z + p[7]*q1.w;
        const float e = __expf(dot * scale);
        sum += e;
        a[0] += e*q0.x; a[1] += e*q0.y; a[2] += e*q0.z; a[3] += e*q0.w;
        a[4] += e*q1.x; a[5] += e*q1.y; a[6] += e*q1.z; a[7] += e*q1.w;
    }
    const float inv = 1.0f / sum;

    unsigned int ow[4];
    #pragma unroll
    for (int d = 0; d < 4; ++d)
        ow[d] = (unsigned int)f2bf(a[2*d]*inv) | ((unsigned int)f2bf(a[2*d+1]*inv) << 16);
    uint4 outv; outv.x = ow[0]; outv.y = ow[1]; outv.z = ow[2]; outv.w = ow[3];

    const int row = (b << 11) + h * 32 + (s >> 6);
    const int col = (s & 63) * DK;
    *(uint4*)(A + (size_t)row * E_DIM + col) = outv;
}

// ---------------------------------------------------------------------------
// Prepass: convert W (512x512 fp32) -> bf16 in ws. 4 elems/thread.
// ---------------------------------------------------------------------------
__global__ __launch_bounds__(256) void convert_w(
    const float* __restrict__ W, unsigned short* __restrict__ Wb)
{
    const int i = blockIdx.x * 256 + threadIdx.x;     // 0..65535
    const float4 v = *(const float4*)(W + (size_t)i * 4);
    ushort4 o;
    o.x = f2bf(v.x); o.y = f2bf(v.y); o.z = f2bf(v.z); o.w = f2bf(v.w);
    *(ushort4*)(Wb + (size_t)i * 4) = o;
}

// ---------------------------------------------------------------------------
// Kernel 2: OUT = A @ W^T + bias.  M=16384, N=K=512. A,W bf16 (ws); bias fp32;
// OUT fp32 (reference output dtype). 128x128 tile, 4 waves (2x2),
// each wave 4x4 mfma 16x16x32 tiles. Register-mediated staging (m93 pattern).
// ---------------------------------------------------------------------------
#define BM 128
#define BN 128
#define BK 32

__global__ __launch_bounds__(256) void gemm_bias(
    const unsigned short* __restrict__ A,     // 16384 x 512 bf16 (ws)
    const unsigned short* __restrict__ W,     // 512 x 512 bf16 (ws)
    const float* __restrict__ BIAS,           // 512 fp32
    float* __restrict__ OUT)                  // 16384 x 512 fp32
{
    const int Kdim = 512;
    __shared__ __align__(16) unsigned short ldsA[BM * BK];  // 8 KB
    __shared__ __align__(16) unsigned short ldsB[BN * BK];  // 8 KB
    const int tid  = threadIdx.x;
    const int wave = tid >> 6;
    const int lane = tid & 63;
    const int quad = lane >> 4;
    const int l16  = lane & 15;
    const int m0 = blockIdx.x * BM;
    const int n0 = blockIdx.y * BN;
    const int wm = (wave & 1) * 64;
    const int wn = (wave >> 1) * 64;

    f32x4 acc[4][4] = {};

    for (int kb = 0; kb < Kdim; kb += BK) {
        uint4 av[2], wvv[2];
        int cc[2];
        #pragma unroll
        for (int i = 0; i < 2; ++i) {
            const int c  = tid + i * 256;       // chunk id 0..511
            const int r  = c >> 2;              // tile row 0..127
            const int ko = (c & 3) * 8;         // k offset in elems
            cc[i] = c;
            av[i]  = *(const uint4*)(A + (size_t)(m0 + r) * Kdim + kb + ko);
            wvv[i] = *(const uint4*)(W + (size_t)(n0 + r) * Kdim + kb + ko);
        }
        __syncthreads();   // previous iteration's readers done
        #pragma unroll
        for (int i = 0; i < 2; ++i) {
            *(uint4*)(ldsA + cc[i] * 8) = av[i];
            *(uint4*)(ldsB + cc[i] * 8) = wvv[i];
        }
        __syncthreads();   // staging visible

        bf16x8 bfr[4];
        #pragma unroll
        for (int ni = 0; ni < 4; ++ni)
            bfr[ni] = *(const bf16x8*)(ldsB + (wn + ni*16 + l16) * BK + quad * 8);
        #pragma unroll
        for (int mi = 0; mi < 4; ++mi) {
            const bf16x8 afr = *(const bf16x8*)(ldsA + (wm + mi*16 + l16) * BK + quad * 8);
            #pragma unroll
            for (int ni = 0; ni < 4; ++ni)
                acc[mi][ni] = __builtin_amdgcn_mfma_f32_16x16x32_bf16(
                    afr, bfr[ni], acc[mi][ni], 0, 0, 0);
        }
    }

    float bv[4];
    #pragma unroll
    for (int ni = 0; ni < 4; ++ni) bv[ni] = BIAS[n0 + wn + ni*16 + l16];

    #pragma unroll
    for (int mi = 0; mi < 4; ++mi) {
        #pragma unroll
        for (int ni = 0; ni < 4; ++ni) {
            const int n = n0 + wn + ni*16 + l16;
            #pragma unroll
            for (int r = 0; r < 4; ++r) {
                const int m = m0 + wm + mi*16 + quad*4 + r;   // C/D: row=(lane>>4)*4+reg
                OUT[(size_t)m * 512 + n] = acc[mi][ni][r] + bv[ni];
            }
        }
    }
}

extern "C" void kernel_launch(void* const* d_in, const int* in_sizes, int n_in,
                              void* d_out, int out_size, void* d_ws, size_t ws_size,
                              hipStream_t stream) {
    const float* X  = (const float*)d_in[0];   // x fp32
    const float* TH = (const float*)d_in[1];   // theta fp32
    const float* W  = (const float*)d_in[2];   // W_combine fp32
    const float* BI = (const float*)d_in[3];   // b_combine fp32
    float* OUT = (float*)d_out;                // fp32 (reference output dtype)

    unsigned short* A  = (unsigned short*)d_ws;                        // 16 MiB
    unsigned short* Wb = (unsigned short*)((char*)d_ws + (16u << 20)); // 512 KiB

    attn_stage<<<dim3(4096), dim3(256), 0, stream>>>(X, TH, A);
    convert_w<<<dim3(256), dim3(256), 0, stream>>>(W, Wb);
    gemm_bias<<<dim3(128, 4), dim3(256), 0, stream>>>(A, Wb, BI, OUT);
}

// Round 6
// 160.755 us; speedup vs baseline: 2.4645x; 1.0721x over previous
//
#include <hip/hip_runtime.h>

typedef __attribute__((ext_vector_type(2))) float  f32x2;
typedef __attribute__((ext_vector_type(4))) float  f32x4;
typedef __attribute__((ext_vector_type(8))) __bf16 bf16x8;

__device__ __forceinline__ unsigned short f2bf(float f) {
    unsigned int u = __float_as_uint(f);
    u += 0x7FFFu + ((u >> 16) & 1u);   // RNE
    return (unsigned short)(u >> 16);
}

#define S_LEN 2048
#define E_DIM 512
#define NH 64
#define DK 8

// ---------------------------------------------------------------------------
// Kernel 1: quantum projection + per-token attention over heads.
// One wave per token, lane = head. Single-pass softmax without max
// subtraction (|score| <= 2.83 -> exp in [0.059,17], no overflow).
// R6: g-loop rewritten in f32x2 so clang emits v_pk_fma_f32 (full-rate
// packed fp32 on CDNA4) -> halves VALU issue for the 16 FMA/g.
// scale*log2e folded into p once; exp2/rcp intrinsics.
// A[row, col]: row = b*2048 + h*32 + s/64 ; col = (s%64)*8 + d
// ---------------------------------------------------------------------------
__global__ __launch_bounds__(256) void attn_stage(
    const float* __restrict__ X,    // (8,2048,512) fp32
    const float* __restrict__ TH,   // (8,) fp32
    unsigned short* __restrict__ A) // ws: 16384 x 512 bf16
{
    __shared__ __align__(16) float ldsP[4][NH][DK];   // 8 KB
    const int wv = threadIdx.x >> 6;
    const int h  = threadIdx.x & 63;
    const int t  = blockIdx.x * 4 + wv;     // token id
    const int b  = t >> 11;
    const int s  = t & (S_LEN - 1);

    const float4 t0 = *(const float4*)(TH);
    const float4 t1 = *(const float4*)(TH + 4);
    const float4 x0 = *(const float4*)(X + (size_t)t * E_DIM + h * DK);
    const float4 x1 = *(const float4*)(X + (size_t)t * E_DIM + h * DK + 4);

    float p[DK];
    p[0] = __cosf(x0.x + t0.x); p[1] = __cosf(x0.y + t0.y);
    p[2] = __cosf(x0.z + t0.z); p[3] = __cosf(x0.w + t0.w);
    p[4] = __cosf(x1.x + t1.x); p[5] = __cosf(x1.y + t1.y);
    p[6] = __cosf(x1.z + t1.z); p[7] = __cosf(x1.w + t1.w);

    {
        f32x4 p01 = {p[0], p[1], p[2], p[3]};
        f32x4 p23 = {p[4], p[5], p[6], p[7]};
        *(f32x4*)&ldsP[wv][h][0] = p01;
        *(f32x4*)&ldsP[wv][h][4] = p23;
    }
    __syncthreads();

    // ps = p * (1/sqrt(8) * log2(e)) so score -> exp2 directly
    const float cfold = 0.35355339059327373f * 1.4426950408889634f;
    f32x2 ps[4];
    ps[0] = f32x2{p[0], p[1]} * cfold;
    ps[1] = f32x2{p[2], p[3]} * cfold;
    ps[2] = f32x2{p[4], p[5]} * cfold;
    ps[3] = f32x2{p[6], p[7]} * cfold;

    float sum = 0.f;
    f32x2 a2[4] = {f32x2{0.f,0.f}, f32x2{0.f,0.f}, f32x2{0.f,0.f}, f32x2{0.f,0.f}};
    #pragma unroll 8
    for (int g = 0; g < NH; ++g) {
        const f32x4 q0 = *(const f32x4*)&ldsP[wv][g][0];   // broadcast (wave-uniform g)
        const f32x4 q1 = *(const f32x4*)&ldsP[wv][g][4];
        const f32x2 qa = __builtin_shufflevector(q0, q0, 0, 1);
        const f32x2 qb = __builtin_shufflevector(q0, q0, 2, 3);
        const f32x2 qc = __builtin_shufflevector(q1, q1, 0, 1);
        const f32x2 qd = __builtin_shufflevector(q1, q1, 2, 3);
        f32x2 d2 = ps[0] * qa;
        d2 += ps[1] * qb;
        d2 += ps[2] * qc;
        d2 += ps[3] * qd;
        const float e = __builtin_amdgcn_exp2f(d2.x + d2.y);
        sum += e;
        const f32x2 e2 = {e, e};
        a2[0] += e2 * qa; a2[1] += e2 * qb;
        a2[2] += e2 * qc; a2[3] += e2 * qd;
    }
    const float inv = __builtin_amdgcn_rcpf(sum);

    unsigned int ow[4];
    #pragma unroll
    for (int d = 0; d < 4; ++d)
        ow[d] = (unsigned int)f2bf(a2[d].x * inv) | ((unsigned int)f2bf(a2[d].y * inv) << 16);
    uint4 outv; outv.x = ow[0]; outv.y = ow[1]; outv.z = ow[2]; outv.w = ow[3];

    const int row = (b << 11) + h * 32 + (s >> 6);
    const int col = (s & 63) * DK;
    *(uint4*)(A + (size_t)row * E_DIM + col) = outv;
}

// ---------------------------------------------------------------------------
// Prepass: convert W (512x512 fp32) -> bf16 in ws. 4 elems/thread.
// ---------------------------------------------------------------------------
__global__ __launch_bounds__(256) void convert_w(
    const float* __restrict__ W, unsigned short* __restrict__ Wb)
{
    const int i = blockIdx.x * 256 + threadIdx.x;     // 0..65535
    const float4 v = *(const float4*)(W + (size_t)i * 4);
    ushort4 o;
    o.x = f2bf(v.x); o.y = f2bf(v.y); o.z = f2bf(v.z); o.w = f2bf(v.w);
    *(ushort4*)(Wb + (size_t)i * 4) = o;
}

// ---------------------------------------------------------------------------
// Kernel 2: OUT = A @ W^T + bias.  M=16384, N=K=512. A,W bf16 (ws); bias fp32;
// OUT fp32. 128x128 tile, 4 waves (2x2), each wave 4x4 mfma 16x16x32 tiles.
// R6: BK=64 (8 K-iters instead of 16 -> half the barrier drains; our MFMA
// time is ~1 us so the loop is barrier/latency-bound) + XOR chunk swizzle
// (16B chunk cc stored at cc^(row&7)) so fragment ds_read_b128 is
// conflict-free (row stride 128B would otherwise alias all 16 l16-lanes
// onto one 4-bank group).
// ---------------------------------------------------------------------------
#define BM 128
#define BN 128
#define BK 64

__global__ __launch_bounds__(256) void gemm_bias(
    const unsigned short* __restrict__ A,     // 16384 x 512 bf16 (ws)
    const unsigned short* __restrict__ W,     // 512 x 512 bf16 (ws)
    const float* __restrict__ BIAS,           // 512 fp32
    float* __restrict__ OUT)                  // 16384 x 512 fp32
{
    const int Kdim = 512;
    __shared__ __align__(16) unsigned short ldsA[BM * BK];  // 16 KB
    __shared__ __align__(16) unsigned short ldsB[BN * BK];  // 16 KB
    const int tid  = threadIdx.x;
    const int lane = tid & 63;
    const int wave = tid >> 6;
    const int quad = lane >> 4;
    const int l16  = lane & 15;
    const int m0 = blockIdx.x * BM;
    const int n0 = blockIdx.y * BN;
    const int wm = (wave & 1) * 64;
    const int wn = (wave >> 1) * 64;

    f32x4 acc[4][4] = {};

    for (int kb = 0; kb < Kdim; kb += BK) {
        // Stage 128x64 bf16 tiles: 1024 16B-chunks each, 4 per thread.
        uint4 av[4], wvv[4];
        int rr[4], sc[4];
        #pragma unroll
        for (int i = 0; i < 4; ++i) {
            const int c  = tid + i * 256;       // chunk id 0..1023
            const int r  = c >> 3;              // tile row 0..127
            const int cc = c & 7;               // 16B chunk within row
            rr[i] = r;
            sc[i] = (cc ^ (r & 7)) * 8;         // swizzled elem offset
            av[i]  = *(const uint4*)(A + (size_t)(m0 + r) * Kdim + kb + cc * 8);
            wvv[i] = *(const uint4*)(W + (size_t)(n0 + r) * Kdim + kb + cc * 8);
        }
        __syncthreads();   // previous iteration's readers done
        #pragma unroll
        for (int i = 0; i < 4; ++i) {
            *(uint4*)(ldsA + rr[i] * BK + sc[i]) = av[i];
            *(uint4*)(ldsB + rr[i] * BK + sc[i]) = wvv[i];
        }
        __syncthreads();   // staging visible

        #pragma unroll
        for (int ks = 0; ks < 2; ++ks) {
            const int swz = ((ks * 4 + quad) ^ (l16 & 7)) * 8;  // row&7 == l16&7
            bf16x8 bfr[4];
            #pragma unroll
            for (int ni = 0; ni < 4; ++ni)
                bfr[ni] = *(const bf16x8*)(ldsB + (wn + ni*16 + l16) * BK + swz);
            #pragma unroll
            for (int mi = 0; mi < 4; ++mi) {
                const bf16x8 afr = *(const bf16x8*)(ldsA + (wm + mi*16 + l16) * BK + swz);
                #pragma unroll
                for (int ni = 0; ni < 4; ++ni)
                    acc[mi][ni] = __builtin_amdgcn_mfma_f32_16x16x32_bf16(
                        afr, bfr[ni], acc[mi][ni], 0, 0, 0);
            }
        }
    }

    float bv[4];
    #pragma unroll
    for (int ni = 0; ni < 4; ++ni) bv[ni] = BIAS[n0 + wn + ni*16 + l16];

    #pragma unroll
    for (int mi = 0; mi < 4; ++mi) {
        #pragma unroll
        for (int ni = 0; ni < 4; ++ni) {
            const int n = n0 + wn + ni*16 + l16;
            #pragma unroll
            for (int r = 0; r < 4; ++r) {
                const int m = m0 + wm + mi*16 + quad*4 + r;   // C/D: row=(lane>>4)*4+reg
                OUT[(size_t)m * 512 + n] = acc[mi][ni][r] + bv[ni];
            }
        }
    }
}

extern "C" void kernel_launch(void* const* d_in, const int* in_sizes, int n_in,
                              void* d_out, int out_size, void* d_ws, size_t ws_size,
                              hipStream_t stream) {
    const float* X  = (const float*)d_in[0];   // x fp32
    const float* TH = (const float*)d_in[1];   // theta fp32
    const float* W  = (const float*)d_in[2];   // W_combine fp32
    const float* BI = (const float*)d_in[3];   // b_combine fp32
    float* OUT = (float*)d_out;                // fp32 (reference output dtype)

    unsigned short* A  = (unsigned short*)d_ws;                        // 16 MiB
    unsigned short* Wb = (unsigned short*)((char*)d_ws + (16u << 20)); // 512 KiB

    attn_stage<<<dim3(4096), dim3(256), 0, stream>>>(X, TH, A);
    convert_w<<<dim3(256), dim3(256), 0, stream>>>(W, Wb);
    gemm_bias<<<dim3(128, 4), dim3(256), 0, stream>>>(A, Wb, BI, OUT);
}